// Round 1
// baseline (898.740 us; speedup 1.0000x reference)
//
#include <hip/hip_runtime.h>
#include <hip/hip_bf16.h>

// Qwen2 attention block: qkv = hs@Wqkv+b; rope(q,k); causal GQA attention; out = attn@Wo
// T=2048 D=3584 HQ=28 HKV=4 DH=128. All matmuls in bf16 MFMA (16x16x32), fp32 accum.

#define T_SEQ 2048
#define D_MODEL 3584
#define HQ 28
#define HKV 4
#define GQA 7
#define DH 128
#define NQKV 4608   // (HQ+2*HKV)*DH
#define KVD 512     // HKV*DH

typedef unsigned short u16;
typedef __attribute__((ext_vector_type(8))) short short8;   // 8 bf16 (4 VGPRs)
typedef __attribute__((ext_vector_type(4))) float floatx4;
typedef __attribute__((ext_vector_type(4))) int intx4;

__device__ __forceinline__ u16 f2b(float x) {               // fp32 -> bf16 RNE
    unsigned u = __float_as_uint(x);
    return (u16)((u + 0x7fffu + ((u >> 16) & 1u)) >> 16);
}

// ---------------- fp32 -> bf16 straight convert ----------------
__global__ void cvt_kernel(const float* __restrict__ in, u16* __restrict__ out, int n) {
    int i = (blockIdx.x * blockDim.x + threadIdx.x) * 4;
    if (i + 3 < n) {
        float4 v = *(const float4*)(in + i);
        u16 o0 = f2b(v.x), o1 = f2b(v.y), o2 = f2b(v.z), o3 = f2b(v.w);
        uint2 pk;
        pk.x = (unsigned)o0 | ((unsigned)o1 << 16);
        pk.y = (unsigned)o2 | ((unsigned)o3 << 16);
        *(uint2*)(out + i) = pk;
    }
}

// ---------------- fp32 (R x C) -> bf16 transposed (C x R) ----------------
__global__ void transpose_cvt(const float* __restrict__ in, u16* __restrict__ out, int R, int C) {
    __shared__ u16 tile[32][33];
    int c0 = blockIdx.x * 32, r0 = blockIdx.y * 32;
    int tx = threadIdx.x, ty = threadIdx.y;   // (32,8)
#pragma unroll
    for (int i = 0; i < 32; i += 8)
        tile[ty + i][tx] = f2b(in[(long)(r0 + ty + i) * C + c0 + tx]);
    __syncthreads();
#pragma unroll
    for (int i = 0; i < 32; i += 8)
        out[(long)(c0 + ty + i) * R + r0 + tx] = tile[tx][ty + i];
}

// ---------------- bf16 GEMM: C = A(MxK) * Bt(NxK)^T + bias, fp32 out ----------------
// 128x128 tile, BK=32, 256 threads = 2x2 waves, each wave 64x64 via 4x4 MFMA 16x16x32.
__global__ __launch_bounds__(256) void gemm_bt(
    const u16* __restrict__ A, const u16* __restrict__ Bt,
    float* __restrict__ C, const float* __restrict__ bias,
    int M, int N, int K)
{
    __shared__ __align__(16) u16 As[128 * 32];
    __shared__ __align__(16) u16 Bs[128 * 32];
    const int tid = threadIdx.x;
    const int lane = tid & 63, wave = tid >> 6;
    const int quad = lane >> 4, l16 = lane & 15;
    const int wm = (wave >> 1) * 64, wn = (wave & 1) * 64;
    const int m0 = blockIdx.y * 128, n0 = blockIdx.x * 128;
    const int srow = tid >> 1, scol = (tid & 1) * 16;

    const u16* Ag = A + (long)(m0 + srow) * K + scol;
    const u16* Bg = Bt + (long)(n0 + srow) * K + scol;
    u16* AsW = As + srow * 32 + scol;
    u16* BsW = Bs + srow * 32 + scol;

    floatx4 acc[4][4] = {};

    for (int k0 = 0; k0 < K; k0 += 32) {
        intx4 a0 = *(const intx4*)(Ag + k0);
        intx4 a1 = *(const intx4*)(Ag + k0 + 8);
        intx4 b0 = *(const intx4*)(Bg + k0);
        intx4 b1 = *(const intx4*)(Bg + k0 + 8);
        __syncthreads();
        *(intx4*)AsW = a0; *(intx4*)(AsW + 8) = a1;
        *(intx4*)BsW = b0; *(intx4*)(BsW + 8) = b1;
        __syncthreads();
        short8 af[4], bfr[4];
#pragma unroll
        for (int i = 0; i < 4; i++)
            af[i] = *(const short8*)(As + (wm + i * 16 + l16) * 32 + quad * 8);
#pragma unroll
        for (int i = 0; i < 4; i++)
            bfr[i] = *(const short8*)(Bs + (wn + i * 16 + l16) * 32 + quad * 8);
#pragma unroll
        for (int mi = 0; mi < 4; mi++)
#pragma unroll
            for (int ni = 0; ni < 4; ni++)
                acc[mi][ni] = __builtin_amdgcn_mfma_f32_16x16x32_bf16(af[mi], bfr[ni], acc[mi][ni], 0, 0, 0);
    }

#pragma unroll
    for (int mi = 0; mi < 4; mi++) {
        int row = m0 + wm + mi * 16 + quad * 4;
#pragma unroll
        for (int ni = 0; ni < 4; ni++) {
            int col = n0 + wn + ni * 16 + l16;
            float b = bias ? bias[col] : 0.0f;
#pragma unroll
            for (int r = 0; r < 4; r++)
                C[(long)(row + r) * N + col] = acc[mi][ni][r] + b;
        }
    }
}

// ---------------- RoPE + split qkv(fp32) -> Qb, Kb bf16; V -> transposed (d, t) bf16 ----------------
__global__ void rope_split(const float* __restrict__ qkv, const int* __restrict__ pos,
                           u16* __restrict__ Qb, u16* __restrict__ Kb, u16* __restrict__ VbT)
{
    int t = blockIdx.x, h = blockIdx.y, j = threadIdx.x;  // j in [0,64)
    const float* row = qkv + (long)t * NQKV + h * DH;
    if (h < HQ + HKV) {
        float x1 = row[j], x2 = row[j + 64];
        // inv_freq = theta^(-j/64) = 2^(-j*log2(1e6)/64)
        float inv = exp2f(-0.311430758889f * (float)j);
        float ang = (float)pos[t] * inv;
        float c = cosf(ang), s = sinf(ang);
        u16 o1 = f2b(x1 * c - x2 * s);
        u16 o2 = f2b(x2 * c + x1 * s);
        if (h < HQ) {
            u16* o = Qb + (long)t * D_MODEL + h * DH;
            o[j] = o1; o[j + 64] = o2;
        } else {
            u16* o = Kb + (long)t * KVD + (h - HQ) * DH;
            o[j] = o1; o[j + 64] = o2;
        }
    } else {
        int hv = h - HQ - HKV;
        VbT[(long)(hv * DH + j) * T_SEQ + t] = f2b(row[j]);
        VbT[(long)(hv * DH + j + 64) * T_SEQ + t] = f2b(row[j + 64]);
    }
}

// ---------------- flash attention, causal, GQA. 4 waves/block, wave = 16 q rows. ----------------
__global__ __launch_bounds__(256) void attn_kernel(
    const u16* __restrict__ Qb, const u16* __restrict__ Kb,
    const u16* __restrict__ VbT, u16* __restrict__ Ob)
{
    __shared__ __align__(16) u16 Ps[4][16 * 72];   // per-wave P tile, padded rows (+8)
    const int h = blockIdx.y;
    const int kvh = h / GQA;
    const int qb = gridDim.x - 1 - blockIdx.x;     // biggest workloads launch first
    const int q0 = qb * 64;
    const int tid = threadIdx.x;
    const int wave = tid >> 6, lane = tid & 63;
    const int quad = lane >> 4, l16 = lane & 15;
    const int qrow = q0 + wave * 16;

    // Q A-frags for this wave's 16 rows, kept in registers (m = l16, k = kc*32+quad*8+j)
    short8 qf[4];
    const u16* qptr = Qb + (long)(qrow + l16) * D_MODEL + h * DH;
#pragma unroll
    for (int kc = 0; kc < 4; kc++)
        qf[kc] = *(const short8*)(qptr + kc * 32 + quad * 8);

    floatx4 acc_o[8] = {};
    float m_run[4] = {-3e38f, -3e38f, -3e38f, -3e38f};
    float l_run[4] = {0.f, 0.f, 0.f, 0.f};
    const float scale = 0.08838834764831845f;   // 1/sqrt(128)
    u16* pw = &Ps[wave][0];

    for (int c0 = 0; c0 <= q0; c0 += 64) {
        // ---- S = Q K^T (C layout: row = quad*4+r, col = l16, per 16-col tile ni) ----
        floatx4 s[4];
#pragma unroll
        for (int ni = 0; ni < 4; ni++) {
            const u16* kptr = Kb + (long)(c0 + ni * 16 + l16) * KVD + kvh * DH;
            floatx4 a = {};
#pragma unroll
            for (int kc = 0; kc < 4; kc++) {
                short8 kf = *(const short8*)(kptr + kc * 32 + quad * 8);
                a = __builtin_amdgcn_mfma_f32_16x16x32_bf16(qf[kc], kf, a, 0, 0, 0);
            }
            s[ni] = a;
        }
        // ---- scale + causal mask ----
        float sv[4][4];
#pragma unroll
        for (int ni = 0; ni < 4; ni++) {
            int col = c0 + ni * 16 + l16;
#pragma unroll
            for (int r = 0; r < 4; r++) {
                float v = s[ni][r] * scale;
                sv[ni][r] = (col > qrow + quad * 4 + r) ? -1e30f : v;
            }
        }
        // ---- online softmax (rows live in 16-lane quad groups) ----
        float tm[4];
#pragma unroll
        for (int r = 0; r < 4; r++)
            tm[r] = fmaxf(fmaxf(sv[0][r], sv[1][r]), fmaxf(sv[2][r], sv[3][r]));
#pragma unroll
        for (int off = 1; off < 16; off <<= 1)
#pragma unroll
            for (int r = 0; r < 4; r++)
                tm[r] = fmaxf(tm[r], __shfl_xor(tm[r], off));
        float alpha[4], rsum[4];
#pragma unroll
        for (int r = 0; r < 4; r++) {
            float nm = fmaxf(m_run[r], tm[r]);
            alpha[r] = __expf(m_run[r] - nm);
            m_run[r] = nm;
            rsum[r] = 0.f;
        }
#pragma unroll
        for (int ni = 0; ni < 4; ni++)
#pragma unroll
            for (int r = 0; r < 4; r++) {
                float p = __expf(sv[ni][r] - m_run[r]);
                sv[ni][r] = p;
                rsum[r] += p;
            }
#pragma unroll
        for (int off = 1; off < 16; off <<= 1)
#pragma unroll
            for (int r = 0; r < 4; r++)
                rsum[r] += __shfl_xor(rsum[r], off);
#pragma unroll
        for (int r = 0; r < 4; r++)
            l_run[r] = l_run[r] * alpha[r] + rsum[r];
#pragma unroll
        for (int o = 0; o < 8; o++)
#pragma unroll
            for (int r = 0; r < 4; r++)
                acc_o[o][r] *= alpha[r];
        // ---- P: C layout -> LDS -> A layout (wave-private region, no barrier needed) ----
#pragma unroll
        for (int ni = 0; ni < 4; ni++)
#pragma unroll
            for (int r = 0; r < 4; r++)
                pw[(quad * 4 + r) * 72 + ni * 16 + l16] = f2b(sv[ni][r]);
        __asm__ volatile("" ::: "memory");
        // ---- O += P V  (V in (d,t) layout -> contiguous k runs) ----
#pragma unroll
        for (int kc = 0; kc < 2; kc++) {
            short8 pf = *(const short8*)(pw + l16 * 72 + kc * 32 + quad * 8);
#pragma unroll
            for (int di = 0; di < 8; di++) {
                const u16* vptr = VbT + (long)(kvh * DH + di * 16 + l16) * T_SEQ + c0 + kc * 32 + quad * 8;
                short8 vf = *(const short8*)vptr;
                acc_o[di] = __builtin_amdgcn_mfma_f32_16x16x32_bf16(pf, vf, acc_o[di], 0, 0, 0);
            }
        }
        __asm__ volatile("" ::: "memory");
    }
    // ---- epilogue: normalize, write bf16 attn output (T x HQ*DH) ----
    float invl[4];
#pragma unroll
    for (int r = 0; r < 4; r++) invl[r] = 1.0f / l_run[r];
#pragma unroll
    for (int di = 0; di < 8; di++)
#pragma unroll
        for (int r = 0; r < 4; r++)
            Ob[(long)(qrow + quad * 4 + r) * D_MODEL + h * DH + di * 16 + l16] =
                f2b(acc_o[di][r] * invl[r]);
}

extern "C" void kernel_launch(void* const* d_in, const int* in_sizes, int n_in,
                              void* d_out, int out_size, void* d_ws, size_t ws_size,
                              hipStream_t stream) {
    const int*   positions = (const int*)d_in[0];
    const float* hidden    = (const float*)d_in[1];
    const float* Wqkv      = (const float*)d_in[2];
    const float* bqkv      = (const float*)d_in[3];
    const float* Wo        = (const float*)d_in[4];
    float* out = (float*)d_out;

    // workspace layout (all offsets 1KB-aligned); total ~138 MB
    char* w = (char*)d_ws;
    u16*   hid_b = (u16*)(w);                                     // 2048*3584 bf16   = 14,680,064 B
    u16*   wqkvT = (u16*)(w + 14680064);                          // 4608*3584 bf16   = 33,030,144 B
    u16*   woT   = (u16*)(w + 14680064 + 33030144);               // 3584*3584 bf16   = 25,690,112 B
    float* qkv32 = (float*)(w + 73400320);                        // 2048*4608 fp32   = 37,748,736 B
    u16*   Qb    = (u16*)(w + 111149056);                         // 2048*3584 bf16
    u16*   Kb    = (u16*)(w + 125829120);                         // 2048*512 bf16    = 2,097,152 B
    u16*   VbT   = (u16*)(w + 127926272);                         // 512*2048 bf16 (transposed)
    u16*   attnb = (u16*)(w + 130023424);                         // 2048*3584 bf16

    int nh = T_SEQ * D_MODEL;
    cvt_kernel<<<nh / 1024, 256, 0, stream>>>(hidden, hid_b, nh);
    transpose_cvt<<<dim3(NQKV / 32, D_MODEL / 32), dim3(32, 8), 0, stream>>>(Wqkv, wqkvT, D_MODEL, NQKV);
    transpose_cvt<<<dim3(D_MODEL / 32, D_MODEL / 32), dim3(32, 8), 0, stream>>>(Wo, woT, D_MODEL, D_MODEL);
    gemm_bt<<<dim3(NQKV / 128, T_SEQ / 128), 256, 0, stream>>>(hid_b, wqkvT, qkv32, bqkv,
                                                              T_SEQ, NQKV, D_MODEL);
    rope_split<<<dim3(T_SEQ, HQ + 2 * HKV), 64, 0, stream>>>(qkv32, positions, Qb, Kb, VbT);
    attn_kernel<<<dim3(T_SEQ / 64, HQ), 256, 0, stream>>>(Qb, Kb, VbT, attnb);
    gemm_bt<<<dim3(D_MODEL / 128, T_SEQ / 128), 256, 0, stream>>>(attnb, woT, out, nullptr,
                                                                 T_SEQ, D_MODEL, D_MODEL);
}

// Round 2
// 699.606 us; speedup vs baseline: 1.2846x; 1.2846x over previous
//
#include <hip/hip_runtime.h>
#include <hip/hip_bf16.h>

// Qwen2 attention block: qkv = hs@Wqkv+b; rope(q,k); causal GQA attention; out = attn@Wo
// T=2048 D=3584 HQ=28 HKV=4 DH=128. All matmuls in bf16 MFMA (16x16x32), fp32 accum.
// R1: flash-decoding split-KV (512-wide chunks) to fix causal load imbalance
//     (R0 attn: 2.5% MfmaUtil, 10.5% occupancy, 495us — tail blocks ran solo).

#define T_SEQ 2048
#define D_MODEL 3584
#define HQ 28
#define HKV 4
#define GQA 7
#define DH 128
#define NQKV 4608   // (HQ+2*HKV)*DH
#define KVD 512     // HKV*DH
#define OPCH 7340032L   // per-chunk partial O elems: 28*2048*128

typedef unsigned short u16;
typedef __attribute__((ext_vector_type(8))) short short8;   // 8 bf16 (4 VGPRs)
typedef __attribute__((ext_vector_type(4))) float floatx4;
typedef __attribute__((ext_vector_type(4))) int intx4;

__device__ __forceinline__ u16 f2b(float x) {               // fp32 -> bf16 RNE
    unsigned u = __float_as_uint(x);
    return (u16)((u + 0x7fffu + ((u >> 16) & 1u)) >> 16);
}
__device__ __forceinline__ float b2f(u16 x) {
    return __uint_as_float((unsigned)x << 16);
}

// ---------------- fp32 -> bf16 straight convert ----------------
__global__ void cvt_kernel(const float* __restrict__ in, u16* __restrict__ out, int n) {
    int i = (blockIdx.x * blockDim.x + threadIdx.x) * 4;
    if (i + 3 < n) {
        float4 v = *(const float4*)(in + i);
        u16 o0 = f2b(v.x), o1 = f2b(v.y), o2 = f2b(v.z), o3 = f2b(v.w);
        uint2 pk;
        pk.x = (unsigned)o0 | ((unsigned)o1 << 16);
        pk.y = (unsigned)o2 | ((unsigned)o3 << 16);
        *(uint2*)(out + i) = pk;
    }
}

// ---------------- fp32 (R x C) -> bf16 transposed (C x R) ----------------
__global__ void transpose_cvt(const float* __restrict__ in, u16* __restrict__ out, int R, int C) {
    __shared__ u16 tile[32][33];
    int c0 = blockIdx.x * 32, r0 = blockIdx.y * 32;
    int tx = threadIdx.x, ty = threadIdx.y;   // (32,8)
#pragma unroll
    for (int i = 0; i < 32; i += 8)
        tile[ty + i][tx] = f2b(in[(long)(r0 + ty + i) * C + c0 + tx]);
    __syncthreads();
#pragma unroll
    for (int i = 0; i < 32; i += 8)
        out[(long)(c0 + ty + i) * R + r0 + tx] = tile[tx][ty + i];
}

// ---------------- bf16 GEMM: C = A(MxK) * Bt(NxK)^T + bias, fp32 out ----------------
__global__ __launch_bounds__(256) void gemm_bt(
    const u16* __restrict__ A, const u16* __restrict__ Bt,
    float* __restrict__ C, const float* __restrict__ bias,
    int M, int N, int K)
{
    __shared__ __align__(16) u16 As[128 * 32];
    __shared__ __align__(16) u16 Bs[128 * 32];
    const int tid = threadIdx.x;
    const int lane = tid & 63, wave = tid >> 6;
    const int quad = lane >> 4, l16 = lane & 15;
    const int wm = (wave >> 1) * 64, wn = (wave & 1) * 64;
    const int m0 = blockIdx.y * 128, n0 = blockIdx.x * 128;
    const int srow = tid >> 1, scol = (tid & 1) * 16;

    const u16* Ag = A + (long)(m0 + srow) * K + scol;
    const u16* Bg = Bt + (long)(n0 + srow) * K + scol;
    u16* AsW = As + srow * 32 + scol;
    u16* BsW = Bs + srow * 32 + scol;

    floatx4 acc[4][4] = {};

    for (int k0 = 0; k0 < K; k0 += 32) {
        intx4 a0 = *(const intx4*)(Ag + k0);
        intx4 a1 = *(const intx4*)(Ag + k0 + 8);
        intx4 b0 = *(const intx4*)(Bg + k0);
        intx4 b1 = *(const intx4*)(Bg + k0 + 8);
        __syncthreads();
        *(intx4*)AsW = a0; *(intx4*)(AsW + 8) = a1;
        *(intx4*)BsW = b0; *(intx4*)(BsW + 8) = b1;
        __syncthreads();
        short8 af[4], bfr[4];
#pragma unroll
        for (int i = 0; i < 4; i++)
            af[i] = *(const short8*)(As + (wm + i * 16 + l16) * 32 + quad * 8);
#pragma unroll
        for (int i = 0; i < 4; i++)
            bfr[i] = *(const short8*)(Bs + (wn + i * 16 + l16) * 32 + quad * 8);
#pragma unroll
        for (int mi = 0; mi < 4; mi++)
#pragma unroll
            for (int ni = 0; ni < 4; ni++)
                acc[mi][ni] = __builtin_amdgcn_mfma_f32_16x16x32_bf16(af[mi], bfr[ni], acc[mi][ni], 0, 0, 0);
    }

#pragma unroll
    for (int mi = 0; mi < 4; mi++) {
        int row = m0 + wm + mi * 16 + quad * 4;
#pragma unroll
        for (int ni = 0; ni < 4; ni++) {
            int col = n0 + wn + ni * 16 + l16;
            float b = bias ? bias[col] : 0.0f;
#pragma unroll
            for (int r = 0; r < 4; r++)
                C[(long)(row + r) * N + col] = acc[mi][ni][r] + b;
        }
    }
}

// ---------------- RoPE + split qkv(fp32) -> Qb (pre-scaled), Kb bf16; V -> (d, t) bf16 ----------------
__global__ void rope_split(const float* __restrict__ qkv, const int* __restrict__ pos,
                           u16* __restrict__ Qb, u16* __restrict__ Kb, u16* __restrict__ VbT)
{
    int t = blockIdx.x, h = blockIdx.y, j = threadIdx.x;  // j in [0,64)
    const float* row = qkv + (long)t * NQKV + h * DH;
    if (h < HQ + HKV) {
        float x1 = row[j], x2 = row[j + 64];
        float inv = exp2f(-0.311430758889f * (float)j);   // theta^(-j/64)
        float ang = (float)pos[t] * inv;
        float c = cosf(ang), s = sinf(ang);
        float o1 = x1 * c - x2 * s;
        float o2 = x2 * c + x1 * s;
        if (h < HQ) {
            const float scale = 0.08838834764831845f;     // 1/sqrt(128) folded into Q
            u16* o = Qb + (long)t * D_MODEL + h * DH;
            o[j] = f2b(o1 * scale); o[j + 64] = f2b(o2 * scale);
        } else {
            u16* o = Kb + (long)t * KVD + (h - HQ) * DH;
            o[j] = f2b(o1); o[j + 64] = f2b(o2);
        }
    } else {
        int hv = h - HQ - HKV;
        VbT[(long)(hv * DH + j) * T_SEQ + t] = f2b(row[j]);
        VbT[(long)(hv * DH + j + 64) * T_SEQ + t] = f2b(row[j + 64]);
    }
}

// ---------------- flash attention, split-KV. Block = 64 q rows x 512 kv chunk. ----------------
// Writes UNNORMALIZED partial O (bf16) + per-row (m, l) fp32.
__global__ __launch_bounds__(256) void attn_kernel(
    const u16* __restrict__ Qb, const u16* __restrict__ Kb, const u16* __restrict__ VbT,
    u16* __restrict__ Op01, u16* __restrict__ Op23, float* __restrict__ ml)
{
    __shared__ __align__(16) u16 Ps[4][16 * 72];
    // decode (qb, chunk) from blockIdx.x in [0,80): tier g has qtiles 8g..8g+7, g+1 chunks
    int bx = blockIdx.x, qb, ch;
    if (bx < 8)       { qb = bx;               ch = 0; }
    else if (bx < 24) { int j = bx - 8;  qb = 8  + (j >> 1); ch = j & 1; }
    else if (bx < 48) { int j = bx - 24; qb = 16 + j / 3;    ch = j % 3; }
    else              { int j = bx - 48; qb = 24 + (j >> 2); ch = j & 3; }
    const int h = blockIdx.y;
    const int kvh = h / GQA;
    const int q0 = qb * 64;
    const int c_lo = ch * 512;
    const int c_hi = min(c_lo + 512, q0 + 64);
    const int tid = threadIdx.x;
    const int wave = tid >> 6, lane = tid & 63;
    const int quad = lane >> 4, l16 = lane & 15;
    const int qrow = q0 + wave * 16;

    short8 qf[4];
    const u16* qptr = Qb + (long)(qrow + l16) * D_MODEL + h * DH;
#pragma unroll
    for (int kc = 0; kc < 4; kc++)
        qf[kc] = *(const short8*)(qptr + kc * 32 + quad * 8);

    floatx4 acc_o[8] = {};
    float m_run[4] = {-3e38f, -3e38f, -3e38f, -3e38f};
    float l_run[4] = {0.f, 0.f, 0.f, 0.f};
    u16* pw = &Ps[wave][0];

    for (int c0 = c_lo; c0 < c_hi; c0 += 64) {
        // ---- S = Q K^T (Q pre-scaled) ----
        floatx4 s[4];
#pragma unroll
        for (int ni = 0; ni < 4; ni++) {
            const u16* kptr = Kb + (long)(c0 + ni * 16 + l16) * KVD + kvh * DH;
            floatx4 a = {};
#pragma unroll
            for (int kc = 0; kc < 4; kc++) {
                short8 kf = *(const short8*)(kptr + kc * 32 + quad * 8);
                a = __builtin_amdgcn_mfma_f32_16x16x32_bf16(qf[kc], kf, a, 0, 0, 0);
            }
            s[ni] = a;
        }
        // ---- causal mask (only tiles that touch the diagonal for this wave) ----
        float sv[4][4];
        if (c0 + 63 > qrow) {
#pragma unroll
            for (int ni = 0; ni < 4; ni++) {
                int col = c0 + ni * 16 + l16;
#pragma unroll
                for (int r = 0; r < 4; r++)
                    sv[ni][r] = (col > qrow + quad * 4 + r) ? -1e30f : s[ni][r];
            }
        } else {
#pragma unroll
            for (int ni = 0; ni < 4; ni++)
#pragma unroll
                for (int r = 0; r < 4; r++)
                    sv[ni][r] = s[ni][r];
        }
        // ---- online softmax (rows live in 16-lane quad groups) ----
        float tm[4];
#pragma unroll
        for (int r = 0; r < 4; r++)
            tm[r] = fmaxf(fmaxf(sv[0][r], sv[1][r]), fmaxf(sv[2][r], sv[3][r]));
#pragma unroll
        for (int off = 1; off < 16; off <<= 1)
#pragma unroll
            for (int r = 0; r < 4; r++)
                tm[r] = fmaxf(tm[r], __shfl_xor(tm[r], off));
        float alpha[4], rsum[4];
#pragma unroll
        for (int r = 0; r < 4; r++) {
            float nm = fmaxf(m_run[r], tm[r]);
            alpha[r] = __expf(m_run[r] - nm);
            m_run[r] = nm;
            rsum[r] = 0.f;
        }
#pragma unroll
        for (int ni = 0; ni < 4; ni++)
#pragma unroll
            for (int r = 0; r < 4; r++) {
                float p = __expf(sv[ni][r] - m_run[r]);
                sv[ni][r] = p;
                rsum[r] += p;
            }
#pragma unroll
        for (int off = 1; off < 16; off <<= 1)
#pragma unroll
            for (int r = 0; r < 4; r++)
                rsum[r] += __shfl_xor(rsum[r], off);
#pragma unroll
        for (int r = 0; r < 4; r++)
            l_run[r] = l_run[r] * alpha[r] + rsum[r];
#pragma unroll
        for (int o = 0; o < 8; o++)
#pragma unroll
            for (int r = 0; r < 4; r++)
                acc_o[o][r] *= alpha[r];
        // ---- P: C layout -> LDS -> A layout (wave-private, no barrier) ----
#pragma unroll
        for (int ni = 0; ni < 4; ni++)
#pragma unroll
            for (int r = 0; r < 4; r++)
                pw[(quad * 4 + r) * 72 + ni * 16 + l16] = f2b(sv[ni][r]);
        __asm__ volatile("" ::: "memory");
        // ---- O += P V ----
#pragma unroll
        for (int kc = 0; kc < 2; kc++) {
            short8 pf = *(const short8*)(pw + l16 * 72 + kc * 32 + quad * 8);
#pragma unroll
            for (int di = 0; di < 8; di++) {
                const u16* vptr = VbT + (long)(kvh * DH + di * 16 + l16) * T_SEQ + c0 + kc * 32 + quad * 8;
                short8 vf = *(const short8*)vptr;
                acc_o[di] = __builtin_amdgcn_mfma_f32_16x16x32_bf16(pf, vf, acc_o[di], 0, 0, 0);
            }
        }
        __asm__ volatile("" ::: "memory");
    }
    // ---- epilogue: write UNNORMALIZED partial O + (m, l) per row ----
    u16* Op = (ch < 2) ? (Op01 + (long)ch * OPCH) : (Op23 + (long)(ch - 2) * OPCH);
#pragma unroll
    for (int di = 0; di < 8; di++)
#pragma unroll
        for (int r = 0; r < 4; r++) {
            int t = qrow + quad * 4 + r;
            Op[((long)h * T_SEQ + t) * DH + di * 16 + l16] = f2b(acc_o[di][r]);
        }
    if (l16 == 0) {
#pragma unroll
        for (int r = 0; r < 4; r++) {
            int t = qrow + quad * 4 + r;
            float2* p = (float2*)(ml + ((long)(ch * HQ + h) * T_SEQ + t) * 2);
            float2 v; v.x = m_run[r]; v.y = l_run[r];
            *p = v;
        }
    }
}

// ---------------- combine split-KV partials: O = sum_c w_c O_c / sum_c w_c l_c ----------------
__global__ __launch_bounds__(256) void reduce_kernel(
    const u16* __restrict__ Op01, const u16* __restrict__ Op23,
    const float* __restrict__ ml, u16* __restrict__ attnb)
{
    int idx = blockIdx.x * 4 + (threadIdx.x >> 6);   // one wave per (h, t)
    int h = idx >> 11, t = idx & 2047;
    int nch = (t >> 9) + 1;                           // chunks valid for this row
    int lane = threadIdx.x & 63;
    float mv[4], lv[4];
    float m = -3e38f;
    for (int c = 0; c < nch; c++) {
        const float2* p = (const float2*)(ml + ((long)(c * HQ + h) * T_SEQ + t) * 2);
        float2 v = *p;
        mv[c] = v.x; lv[c] = v.y;
        m = fmaxf(m, v.x);
    }
    float lsum = 0.f, o0 = 0.f, o1 = 0.f;
    for (int c = 0; c < nch; c++) {
        float w = __expf(mv[c] - m);
        lsum += w * lv[c];
        const u16* Op = (c < 2) ? (Op01 + (long)c * OPCH) : (Op23 + (long)(c - 2) * OPCH);
        const u16* p = Op + ((long)h * T_SEQ + t) * DH + lane * 2;
        o0 += w * b2f(p[0]);
        o1 += w * b2f(p[1]);
    }
    float inv = 1.0f / lsum;
    unsigned pk = (unsigned)f2b(o0 * inv) | ((unsigned)f2b(o1 * inv) << 16);
    *(unsigned*)(attnb + (long)t * D_MODEL + h * DH + lane * 2) = pk;
}

extern "C" void kernel_launch(void* const* d_in, const int* in_sizes, int n_in,
                              void* d_out, int out_size, void* d_ws, size_t ws_size,
                              hipStream_t stream) {
    const int*   positions = (const int*)d_in[0];
    const float* hidden    = (const float*)d_in[1];
    const float* Wqkv      = (const float*)d_in[2];
    const float* bqkv      = (const float*)d_in[3];
    const float* Wo        = (const float*)d_in[4];
    float* out = (float*)d_out;

    // workspace layout (max used 134.2 MB; regions reused across phases):
    char* w = (char*)d_ws;
    u16*   woT    = (u16*)(w);                      // [0, 25.69M) persist
    u16*   hid_b  = (u16*)(w + 26214400);           // [25M+, 14.68M) dead after gemm1
    u16*   wqkvT  = (u16*)(w + 41943040);           // [40M+, 33.03M) dead after gemm1
    float* qkv32  = (float*)(w + 75497472);         // [72M+, 37.75M) dead after rope
    u16*   Qb     = (u16*)(w + 115343360);          // persist
    u16*   Kb     = (u16*)(w + 130023424);          // persist
    u16*   VbT    = (u16*)(w + 132120576);          // persist, ends 134.2M
    u16*   attnb  = (u16*)(w + 26214400);           // reuse hid_b region
    u16*   Op01   = (u16*)(w + 41943040);           // partial O chunks 0,1 over wqkvT
    u16*   Op23   = (u16*)(w + 75497472);           // partial O chunks 2,3 over qkv32
    float* mlbuf  = (float*)(w + 105906176);        // (m,l) per (chunk,head,row), 1.84M

    int nh = T_SEQ * D_MODEL;
    cvt_kernel<<<nh / 1024, 256, 0, stream>>>(hidden, hid_b, nh);
    transpose_cvt<<<dim3(NQKV / 32, D_MODEL / 32), dim3(32, 8), 0, stream>>>(Wqkv, wqkvT, D_MODEL, NQKV);
    transpose_cvt<<<dim3(D_MODEL / 32, D_MODEL / 32), dim3(32, 8), 0, stream>>>(Wo, woT, D_MODEL, D_MODEL);
    gemm_bt<<<dim3(NQKV / 128, T_SEQ / 128), 256, 0, stream>>>(hid_b, wqkvT, qkv32, bqkv,
                                                              T_SEQ, NQKV, D_MODEL);
    rope_split<<<dim3(T_SEQ, HQ + 2 * HKV), 64, 0, stream>>>(qkv32, positions, Qb, Kb, VbT);
    attn_kernel<<<dim3(80, HQ), 256, 0, stream>>>(Qb, Kb, VbT, Op01, Op23, mlbuf);
    reduce_kernel<<<T_SEQ * HQ / 4, 256, 0, stream>>>(Op01, Op23, mlbuf, attnb);
    gemm_bt<<<dim3(D_MODEL / 128, T_SEQ / 128), 256, 0, stream>>>(attnb, woT, out, nullptr,
                                                                 T_SEQ, D_MODEL, D_MODEL);
}

// Round 3
// 500.007 us; speedup vs baseline: 1.7975x; 1.3992x over previous
//
#include <hip/hip_runtime.h>
#include <hip/hip_bf16.h>

// Qwen2 attention block: qkv = hs@Wqkv+b; rope(q,k); causal GQA attention; out = attn@Wo
// T=2048 D=3584 HQ=28 HKV=4 DH=128. All matmuls in bf16 MFMA (16x16x32), fp32 accum.
// R1: flash-decoding split-KV (512 chunks) — 495->279us, still latency-bound (Mfma 4.5%).
// R2: LDS-stage K/V via global_load_lds (XOR-swizzled, dbuf, 1 barrier/iter) to kill
//     the exposed ~300cyc/load inline global latency; same staging for both GEMMs.

#define T_SEQ 2048
#define D_MODEL 3584
#define HQ 28
#define HKV 4
#define GQA 7
#define DH 128
#define NQKV 4608   // (HQ+2*HKV)*DH
#define KVD 512     // HKV*DH
#define OPCH 7340032L   // per-chunk partial O elems: 28*2048*128

typedef unsigned short u16;
typedef __attribute__((ext_vector_type(8))) short short8;   // 8 bf16 (4 VGPRs)
typedef __attribute__((ext_vector_type(4))) float floatx4;
typedef __attribute__((ext_vector_type(4))) int intx4;

__device__ __forceinline__ u16 f2b(float x) {               // fp32 -> bf16 RNE
    unsigned u = __float_as_uint(x);
    return (u16)((u + 0x7fffu + ((u >> 16) & 1u)) >> 16);
}
__device__ __forceinline__ float b2f(u16 x) {
    return __uint_as_float((unsigned)x << 16);
}
__device__ __forceinline__ void gl_lds16(const u16* g, u16* l) {
    // async global->LDS, 16B/lane; LDS dest = wave-uniform base + lane*16
    __builtin_amdgcn_global_load_lds((const __attribute__((address_space(1))) void*)g,
                                     (__attribute__((address_space(3))) void*)l, 16, 0, 0);
}

// ---------------- fp32 -> bf16 straight convert ----------------
__global__ void cvt_kernel(const float* __restrict__ in, u16* __restrict__ out, int n) {
    int i = (blockIdx.x * blockDim.x + threadIdx.x) * 4;
    if (i + 3 < n) {
        float4 v = *(const float4*)(in + i);
        u16 o0 = f2b(v.x), o1 = f2b(v.y), o2 = f2b(v.z), o3 = f2b(v.w);
        uint2 pk;
        pk.x = (unsigned)o0 | ((unsigned)o1 << 16);
        pk.y = (unsigned)o2 | ((unsigned)o3 << 16);
        *(uint2*)(out + i) = pk;
    }
}

// ---------------- fp32 (R x C) -> bf16 transposed (C x R) ----------------
__global__ void transpose_cvt(const float* __restrict__ in, u16* __restrict__ out, int R, int C) {
    __shared__ u16 tile[32][33];
    int c0 = blockIdx.x * 32, r0 = blockIdx.y * 32;
    int tx = threadIdx.x, ty = threadIdx.y;   // (32,8)
#pragma unroll
    for (int i = 0; i < 32; i += 8)
        tile[ty + i][tx] = f2b(in[(long)(r0 + ty + i) * C + c0 + tx]);
    __syncthreads();
#pragma unroll
    for (int i = 0; i < 32; i += 8)
        out[(long)(c0 + ty + i) * R + r0 + tx] = tile[tx][ty + i];
}

// ---------------- bf16 GEMM: C = A(MxK) * Bt(NxK)^T + bias, fp32 out ----------------
// 128x128 tile, BK=32, global_load_lds staging, double-buffered, 1 barrier/iter.
__global__ __launch_bounds__(256) void gemm_bt(
    const u16* __restrict__ A, const u16* __restrict__ Bt,
    float* __restrict__ C, const float* __restrict__ bias,
    int M, int N, int K)
{
    __shared__ __align__(16) u16 As[2][128 * 32];
    __shared__ __align__(16) u16 Bs[2][128 * 32];
    const int tid = threadIdx.x;
    const int lane = tid & 63, wave = tid >> 6;
    const int quad = lane >> 4, l16 = lane & 15;
    const int wm = (wave >> 1) * 64, wn = (wave & 1) * 64;
    const int m0 = blockIdx.y * 128, n0 = blockIdx.x * 128;
    const int srow = lane >> 2, scb = lane & 3;     // staging: row-in-16, 16B col-block

    floatx4 acc[4][4] = {};

    auto stage = [&](int k0, int b) {
#pragma unroll
        for (int j = 0; j < 2; j++) {
            int r = wave * 32 + j * 16 + srow;
            const u16* ga = A + (long)(m0 + r) * K + k0 + scb * 8;
            const u16* gb = Bt + (long)(n0 + r) * K + k0 + scb * 8;
            gl_lds16(ga, &As[b][(wave * 32 + j * 16) * 32]);
            gl_lds16(gb, &Bs[b][(wave * 32 + j * 16) * 32]);
        }
    };

    stage(0, 0);
    int it = 0;
    for (int k0 = 0; k0 < K; k0 += 32, it++) {
        int b = it & 1;
        __syncthreads();                       // drains vmcnt: tile b ready; prev readers done
        if (k0 + 32 < K) stage(k0 + 32, b ^ 1);
        short8 af[4], bfr[4];
#pragma unroll
        for (int i = 0; i < 4; i++)
            af[i] = *(const short8*)(&As[b][0] + (wm + i * 16 + l16) * 32 + quad * 8);
#pragma unroll
        for (int i = 0; i < 4; i++)
            bfr[i] = *(const short8*)(&Bs[b][0] + (wn + i * 16 + l16) * 32 + quad * 8);
#pragma unroll
        for (int mi = 0; mi < 4; mi++)
#pragma unroll
            for (int ni = 0; ni < 4; ni++)
                acc[mi][ni] = __builtin_amdgcn_mfma_f32_16x16x32_bf16(af[mi], bfr[ni], acc[mi][ni], 0, 0, 0);
    }

#pragma unroll
    for (int mi = 0; mi < 4; mi++) {
        int row = m0 + wm + mi * 16 + quad * 4;
#pragma unroll
        for (int ni = 0; ni < 4; ni++) {
            int col = n0 + wn + ni * 16 + l16;
            float b = bias ? bias[col] : 0.0f;
#pragma unroll
            for (int r = 0; r < 4; r++)
                C[(long)(row + r) * N + col] = acc[mi][ni][r] + b;
        }
    }
}

// ---------------- RoPE + split qkv(fp32) -> Qb (pre-scaled), Kb bf16; V -> (d, t) bf16 ----------------
__global__ void rope_split(const float* __restrict__ qkv, const int* __restrict__ pos,
                           u16* __restrict__ Qb, u16* __restrict__ Kb, u16* __restrict__ VbT)
{
    int t = blockIdx.x, h = blockIdx.y, j = threadIdx.x;  // j in [0,64)
    const float* row = qkv + (long)t * NQKV + h * DH;
    if (h < HQ + HKV) {
        float x1 = row[j], x2 = row[j + 64];
        float inv = exp2f(-0.311430758889f * (float)j);   // theta^(-j/64)
        float ang = (float)pos[t] * inv;
        float c = cosf(ang), s = sinf(ang);
        float o1 = x1 * c - x2 * s;
        float o2 = x2 * c + x1 * s;
        if (h < HQ) {
            const float scale = 0.08838834764831845f;     // 1/sqrt(128) folded into Q
            u16* o = Qb + (long)t * D_MODEL + h * DH;
            o[j] = f2b(o1 * scale); o[j + 64] = f2b(o2 * scale);
        } else {
            u16* o = Kb + (long)t * KVD + (h - HQ) * DH;
            o[j] = f2b(o1); o[j + 64] = f2b(o2);
        }
    } else {
        int hv = h - HQ - HKV;
        VbT[(long)(hv * DH + j) * T_SEQ + t] = f2b(row[j]);
        VbT[(long)(hv * DH + j + 64) * T_SEQ + t] = f2b(row[j + 64]);
    }
}

// ---------------- flash attention, split-KV. Block = 64 q rows x 512 kv chunk. ----------------
// K/V tiles staged to LDS via global_load_lds (XOR col-block swizzle vs row&7), dbuf.
__global__ __launch_bounds__(256) void attn_kernel(
    const u16* __restrict__ Qb, const u16* __restrict__ Kb, const u16* __restrict__ VbT,
    u16* __restrict__ Op01, u16* __restrict__ Op23, float* __restrict__ ml)
{
    __shared__ __align__(16) u16 Kt[2][64 * 128];   // [kv 64][d 128], swizzled
    __shared__ __align__(16) u16 Vt[2][128 * 64];   // [d 128][t 64], swizzled
    __shared__ __align__(16) u16 Ps[4][16 * 72];
    // decode (qb, chunk): tier g has qtiles 8g..8g+7, g+1 chunks
    int bx = blockIdx.x, qb, ch;
    if (bx < 8)       { qb = bx;               ch = 0; }
    else if (bx < 24) { int j = bx - 8;  qb = 8  + (j >> 1); ch = j & 1; }
    else if (bx < 48) { int j = bx - 24; qb = 16 + j / 3;    ch = j % 3; }
    else              { int j = bx - 48; qb = 24 + (j >> 2); ch = j & 3; }
    const int h = blockIdx.y;
    const int kvh = h / GQA;
    const int q0 = qb * 64;
    const int c_lo = ch * 512;
    const int c_hi = min(c_lo + 512, q0 + 64);
    const int n_it = (c_hi - c_lo) >> 6;
    const int tid = threadIdx.x;
    const int wave = tid >> 6, lane = tid & 63;
    const int quad = lane >> 4, l16 = lane & 15;
    const int qrow = q0 + wave * 16;
    const int krow_l = lane >> 4, kcb = lane & 15;   // K staging lane coords
    const int vrow_l = lane >> 3, vcb = lane & 7;    // V staging lane coords

    auto stage = [&](int itx, int b) {
        int c0 = c_lo + (itx << 6);
#pragma unroll
        for (int j = 0; j < 4; j++) {                 // K: 4 rows x 256B per instr
            int row = wave * 16 + j * 4 + krow_l;
            int gcb = (kcb & 8) | ((kcb & 7) ^ (row & 7));
            const u16* g = Kb + (long)(c0 + row) * KVD + kvh * DH + gcb * 8;
            gl_lds16(g, &Kt[b][(wave * 16 + j * 4) * 128]);
        }
#pragma unroll
        for (int j = 0; j < 4; j++) {                 // V: 8 rows x 128B per instr
            int row = wave * 32 + j * 8 + vrow_l;
            int gcb = vcb ^ (row & 7);
            const u16* g = VbT + (long)(kvh * DH + row) * T_SEQ + c0 + gcb * 8;
            gl_lds16(g, &Vt[b][(wave * 32 + j * 8) * 64]);
        }
    };

    short8 qf[4];
    const u16* qptr = Qb + (long)(qrow + l16) * D_MODEL + h * DH;
#pragma unroll
    for (int kc = 0; kc < 4; kc++)
        qf[kc] = *(const short8*)(qptr + kc * 32 + quad * 8);

    floatx4 acc_o[8] = {};
    float m_run[4] = {-3e38f, -3e38f, -3e38f, -3e38f};
    float l_run[4] = {0.f, 0.f, 0.f, 0.f};
    u16* pw = &Ps[wave][0];

    stage(0, 0);

    for (int itx = 0; itx < n_it; itx++) {
        int b = itx & 1;
        int c0 = c_lo + (itx << 6);
        __syncthreads();                    // drains my staging loads; all waves' tile b ready
        if (itx + 1 < n_it) stage(itx + 1, b ^ 1);   // prefetch flies during compute
        const u16* Kc = &Kt[b][0];
        const u16* Vc = &Vt[b][0];
        // ---- S = Q K^T (Q pre-scaled) ----
        floatx4 s[4];
#pragma unroll
        for (int ni = 0; ni < 4; ni++) {
            floatx4 a = {};
#pragma unroll
            for (int kc = 0; kc < 4; kc++) {
                int c = kc * 4 + quad;
                int cs = (c & 8) | ((c & 7) ^ (l16 & 7));
                short8 kf = *(const short8*)(Kc + (ni * 16 + l16) * 128 + cs * 8);
                a = __builtin_amdgcn_mfma_f32_16x16x32_bf16(qf[kc], kf, a, 0, 0, 0);
            }
            s[ni] = a;
        }
        // ---- causal mask (only tiles touching the diagonal for this wave) ----
        float sv[4][4];
        if (c0 + 63 > qrow) {
#pragma unroll
            for (int ni = 0; ni < 4; ni++) {
                int col = c0 + ni * 16 + l16;
#pragma unroll
                for (int r = 0; r < 4; r++)
                    sv[ni][r] = (col > qrow + quad * 4 + r) ? -1e30f : s[ni][r];
            }
        } else {
#pragma unroll
            for (int ni = 0; ni < 4; ni++)
#pragma unroll
                for (int r = 0; r < 4; r++)
                    sv[ni][r] = s[ni][r];
        }
        // ---- online softmax (rows live in 16-lane quad groups) ----
        float tm[4];
#pragma unroll
        for (int r = 0; r < 4; r++)
            tm[r] = fmaxf(fmaxf(sv[0][r], sv[1][r]), fmaxf(sv[2][r], sv[3][r]));
#pragma unroll
        for (int off = 1; off < 16; off <<= 1)
#pragma unroll
            for (int r = 0; r < 4; r++)
                tm[r] = fmaxf(tm[r], __shfl_xor(tm[r], off));
        float alpha[4], rsum[4];
#pragma unroll
        for (int r = 0; r < 4; r++) {
            float nm = fmaxf(m_run[r], tm[r]);
            alpha[r] = __expf(m_run[r] - nm);
            m_run[r] = nm;
            rsum[r] = 0.f;
        }
#pragma unroll
        for (int ni = 0; ni < 4; ni++)
#pragma unroll
            for (int r = 0; r < 4; r++) {
                float p = __expf(sv[ni][r] - m_run[r]);
                sv[ni][r] = p;
                rsum[r] += p;
            }
#pragma unroll
        for (int off = 1; off < 16; off <<= 1)
#pragma unroll
            for (int r = 0; r < 4; r++)
                rsum[r] += __shfl_xor(rsum[r], off);
#pragma unroll
        for (int r = 0; r < 4; r++)
            l_run[r] = l_run[r] * alpha[r] + rsum[r];
#pragma unroll
        for (int o = 0; o < 8; o++)
#pragma unroll
            for (int r = 0; r < 4; r++)
                acc_o[o][r] *= alpha[r];
        // ---- P: C layout -> LDS -> A layout (wave-private, no barrier) ----
#pragma unroll
        for (int ni = 0; ni < 4; ni++)
#pragma unroll
            for (int r = 0; r < 4; r++)
                pw[(quad * 4 + r) * 72 + ni * 16 + l16] = f2b(sv[ni][r]);
        __asm__ volatile("" ::: "memory");
        // ---- O += P V ----
#pragma unroll
        for (int kc = 0; kc < 2; kc++) {
            short8 pf = *(const short8*)(pw + l16 * 72 + kc * 32 + quad * 8);
#pragma unroll
            for (int di = 0; di < 8; di++) {
                int c = kc * 4 + quad;
                int cs = c ^ (l16 & 7);
                short8 vf = *(const short8*)(Vc + (di * 16 + l16) * 64 + cs * 8);
                acc_o[di] = __builtin_amdgcn_mfma_f32_16x16x32_bf16(pf, vf, acc_o[di], 0, 0, 0);
            }
        }
        __asm__ volatile("" ::: "memory");
    }
    // ---- epilogue: write UNNORMALIZED partial O + (m, l) per row ----
    u16* Op = (ch < 2) ? (Op01 + (long)ch * OPCH) : (Op23 + (long)(ch - 2) * OPCH);
#pragma unroll
    for (int di = 0; di < 8; di++)
#pragma unroll
        for (int r = 0; r < 4; r++) {
            int t = qrow + quad * 4 + r;
            Op[((long)h * T_SEQ + t) * DH + di * 16 + l16] = f2b(acc_o[di][r]);
        }
    if (l16 == 0) {
#pragma unroll
        for (int r = 0; r < 4; r++) {
            int t = qrow + quad * 4 + r;
            float2* p = (float2*)(ml + ((long)(ch * HQ + h) * T_SEQ + t) * 2);
            float2 v; v.x = m_run[r]; v.y = l_run[r];
            *p = v;
        }
    }
}

// ---------------- combine split-KV partials: O = sum_c w_c O_c / sum_c w_c l_c ----------------
__global__ __launch_bounds__(256) void reduce_kernel(
    const u16* __restrict__ Op01, const u16* __restrict__ Op23,
    const float* __restrict__ ml, u16* __restrict__ attnb)
{
    int idx = blockIdx.x * 4 + (threadIdx.x >> 6);   // one wave per (h, t)
    int h = idx >> 11, t = idx & 2047;
    int nch = (t >> 9) + 1;                           // chunks valid for this row
    int lane = threadIdx.x & 63;
    float mv[4], lv[4];
    float m = -3e38f;
    for (int c = 0; c < nch; c++) {
        const float2* p = (const float2*)(ml + ((long)(c * HQ + h) * T_SEQ + t) * 2);
        float2 v = *p;
        mv[c] = v.x; lv[c] = v.y;
        m = fmaxf(m, v.x);
    }
    float lsum = 0.f, o0 = 0.f, o1 = 0.f;
    for (int c = 0; c < nch; c++) {
        float w = __expf(mv[c] - m);
        lsum += w * lv[c];
        const u16* Op = (c < 2) ? (Op01 + (long)c * OPCH) : (Op23 + (long)(c - 2) * OPCH);
        const u16* p = Op + ((long)h * T_SEQ + t) * DH + lane * 2;
        o0 += w * b2f(p[0]);
        o1 += w * b2f(p[1]);
    }
    float inv = 1.0f / lsum;
    unsigned pk = (unsigned)f2b(o0 * inv) | ((unsigned)f2b(o1 * inv) << 16);
    *(unsigned*)(attnb + (long)t * D_MODEL + h * DH + lane * 2) = pk;
}

extern "C" void kernel_launch(void* const* d_in, const int* in_sizes, int n_in,
                              void* d_out, int out_size, void* d_ws, size_t ws_size,
                              hipStream_t stream) {
    const int*   positions = (const int*)d_in[0];
    const float* hidden    = (const float*)d_in[1];
    const float* Wqkv      = (const float*)d_in[2];
    const float* bqkv      = (const float*)d_in[3];
    const float* Wo        = (const float*)d_in[4];
    float* out = (float*)d_out;

    // workspace layout (max used 134.2 MB; regions reused across phases):
    char* w = (char*)d_ws;
    u16*   woT    = (u16*)(w);                      // [0, 25.69M) persist
    u16*   hid_b  = (u16*)(w + 26214400);           // dead after gemm1
    u16*   wqkvT  = (u16*)(w + 41943040);           // dead after gemm1
    float* qkv32  = (float*)(w + 75497472);         // dead after rope
    u16*   Qb     = (u16*)(w + 115343360);          // persist
    u16*   Kb     = (u16*)(w + 130023424);          // persist
    u16*   VbT    = (u16*)(w + 132120576);          // persist, ends 134.2M
    u16*   attnb  = (u16*)(w + 26214400);           // reuse hid_b region
    u16*   Op01   = (u16*)(w + 41943040);           // partial O chunks 0,1 over wqkvT
    u16*   Op23   = (u16*)(w + 75497472);           // partial O chunks 2,3 over qkv32
    float* mlbuf  = (float*)(w + 105906176);        // (m,l) per (chunk,head,row), 1.84M

    int nh = T_SEQ * D_MODEL;
    cvt_kernel<<<nh / 1024, 256, 0, stream>>>(hidden, hid_b, nh);
    transpose_cvt<<<dim3(NQKV / 32, D_MODEL / 32), dim3(32, 8), 0, stream>>>(Wqkv, wqkvT, D_MODEL, NQKV);
    transpose_cvt<<<dim3(D_MODEL / 32, D_MODEL / 32), dim3(32, 8), 0, stream>>>(Wo, woT, D_MODEL, D_MODEL);
    gemm_bt<<<dim3(NQKV / 128, T_SEQ / 128), 256, 0, stream>>>(hid_b, wqkvT, qkv32, bqkv,
                                                              T_SEQ, NQKV, D_MODEL);
    rope_split<<<dim3(T_SEQ, HQ + 2 * HKV), 64, 0, stream>>>(qkv32, positions, Qb, Kb, VbT);
    attn_kernel<<<dim3(80, HQ), 256, 0, stream>>>(Qb, Kb, VbT, Op01, Op23, mlbuf);
    reduce_kernel<<<T_SEQ * HQ / 4, 256, 0, stream>>>(Op01, Op23, mlbuf, attnb);
    gemm_bt<<<dim3(D_MODEL / 128, T_SEQ / 128), 256, 0, stream>>>(attnb, woT, out, nullptr,
                                                                 T_SEQ, D_MODEL, D_MODEL);
}

// Round 4
// 468.587 us; speedup vs baseline: 1.9180x; 1.0671x over previous
//
#include <hip/hip_runtime.h>
#include <hip/hip_bf16.h>

// Qwen2 attention block: qkv = hs@Wqkv+b; rope(q,k); causal GQA attention; out = attn@Wo
// T=2048 D=3584 HQ=28 HKV=4 DH=128. All matmuls in bf16 MFMA (16x16x32), fp32 accum.
// R1: flash-decoding split-KV — 495->279us. R2: LDS-staged K/V dbuf — 279->118us,
//     but 73KB LDS -> 2 blocks/CU, latency chain exposed (Mfma 10%, Occ 17%).
// R3: 40KB LDS (single-buf K/V, cross-staged, 2 barriers/iter) -> 4 blocks/CU;
//     S^T softmax (2 shuffles not 32), exp2 domain, v_perm bf16 pack.

#define T_SEQ 2048
#define D_MODEL 3584
#define HQ 28
#define HKV 4
#define GQA 7
#define DH 128
#define NQKV 4608   // (HQ+2*HKV)*DH
#define KVD 512     // HKV*DH
#define OPCH 7340032L   // per-chunk partial O elems: 28*2048*128

typedef unsigned short u16;
typedef __attribute__((ext_vector_type(8))) short short8;   // 8 bf16 (4 VGPRs)
typedef __attribute__((ext_vector_type(4))) float floatx4;
typedef __attribute__((ext_vector_type(4))) int intx4;

__device__ __forceinline__ u16 f2b(float x) {               // fp32 -> bf16 RNE
    unsigned u = __float_as_uint(x);
    return (u16)((u + 0x7fffu + ((u >> 16) & 1u)) >> 16);
}
__device__ __forceinline__ float b2f(u16 x) {
    return __uint_as_float((unsigned)x << 16);
}
__device__ __forceinline__ void gl_lds16(const u16* g, u16* l) {
    // async global->LDS, 16B/lane; LDS dest = wave-uniform base + lane*16
    __builtin_amdgcn_global_load_lds((const __attribute__((address_space(1))) void*)g,
                                     (__attribute__((address_space(3))) void*)l, 16, 0, 0);
}

// ---------------- fp32 -> bf16 straight convert ----------------
__global__ void cvt_kernel(const float* __restrict__ in, u16* __restrict__ out, int n) {
    int i = (blockIdx.x * blockDim.x + threadIdx.x) * 4;
    if (i + 3 < n) {
        float4 v = *(const float4*)(in + i);
        u16 o0 = f2b(v.x), o1 = f2b(v.y), o2 = f2b(v.z), o3 = f2b(v.w);
        uint2 pk;
        pk.x = (unsigned)o0 | ((unsigned)o1 << 16);
        pk.y = (unsigned)o2 | ((unsigned)o3 << 16);
        *(uint2*)(out + i) = pk;
    }
}

// ---------------- fp32 (R x C) -> bf16 transposed (C x R) ----------------
__global__ void transpose_cvt(const float* __restrict__ in, u16* __restrict__ out, int R, int C) {
    __shared__ u16 tile[32][33];
    int c0 = blockIdx.x * 32, r0 = blockIdx.y * 32;
    int tx = threadIdx.x, ty = threadIdx.y;   // (32,8)
#pragma unroll
    for (int i = 0; i < 32; i += 8)
        tile[ty + i][tx] = f2b(in[(long)(r0 + ty + i) * C + c0 + tx]);
    __syncthreads();
#pragma unroll
    for (int i = 0; i < 32; i += 8)
        out[(long)(c0 + ty + i) * R + r0 + tx] = tile[tx][ty + i];
}

// ---------------- bf16 GEMM: C = A(MxK) * Bt(NxK)^T + bias, fp32 out ----------------
// 128x128 tile, BK=32, global_load_lds staging, double-buffered, 1 barrier/iter.
__global__ __launch_bounds__(256) void gemm_bt(
    const u16* __restrict__ A, const u16* __restrict__ Bt,
    float* __restrict__ C, const float* __restrict__ bias,
    int M, int N, int K)
{
    __shared__ __align__(16) u16 As[2][128 * 32];
    __shared__ __align__(16) u16 Bs[2][128 * 32];
    const int tid = threadIdx.x;
    const int lane = tid & 63, wave = tid >> 6;
    const int quad = lane >> 4, l16 = lane & 15;
    const int wm = (wave >> 1) * 64, wn = (wave & 1) * 64;
    const int m0 = blockIdx.y * 128, n0 = blockIdx.x * 128;

    floatx4 acc[4][4] = {};

    auto stage = [&](int k0, int b) {
#pragma unroll
        for (int j = 0; j < 2; j++) {
            int r = wave * 32 + j * 16 + (lane >> 2);
            const u16* ga = A + (long)(m0 + r) * K + k0 + (lane & 3) * 8;
            const u16* gb = Bt + (long)(n0 + r) * K + k0 + (lane & 3) * 8;
            gl_lds16(ga, &As[b][(wave * 32 + j * 16) * 32]);
            gl_lds16(gb, &Bs[b][(wave * 32 + j * 16) * 32]);
        }
    };

    stage(0, 0);
    int it = 0;
    for (int k0 = 0; k0 < K; k0 += 32, it++) {
        int b = it & 1;
        __syncthreads();
        if (k0 + 32 < K) stage(k0 + 32, b ^ 1);
        short8 af[4], bfr[4];
#pragma unroll
        for (int i = 0; i < 4; i++)
            af[i] = *(const short8*)(&As[b][0] + (wm + i * 16 + l16) * 32 + quad * 8);
#pragma unroll
        for (int i = 0; i < 4; i++)
            bfr[i] = *(const short8*)(&Bs[b][0] + (wn + i * 16 + l16) * 32 + quad * 8);
#pragma unroll
        for (int mi = 0; mi < 4; mi++)
#pragma unroll
            for (int ni = 0; ni < 4; ni++)
                acc[mi][ni] = __builtin_amdgcn_mfma_f32_16x16x32_bf16(af[mi], bfr[ni], acc[mi][ni], 0, 0, 0);
    }

#pragma unroll
    for (int mi = 0; mi < 4; mi++) {
        int row = m0 + wm + mi * 16 + quad * 4;
#pragma unroll
        for (int ni = 0; ni < 4; ni++) {
            int col = n0 + wn + ni * 16 + l16;
            float b = bias ? bias[col] : 0.0f;
#pragma unroll
            for (int r = 0; r < 4; r++)
                C[(long)(row + r) * N + col] = acc[mi][ni][r] + b;
        }
    }
}

// ---------------- RoPE + split; Q pre-scaled by (1/sqrt(DH))*log2(e) for exp2 softmax ----------------
__global__ void rope_split(const float* __restrict__ qkv, const int* __restrict__ pos,
                           u16* __restrict__ Qb, u16* __restrict__ Kb, u16* __restrict__ VbT)
{
    int t = blockIdx.x, h = blockIdx.y, j = threadIdx.x;  // j in [0,64)
    const float* row = qkv + (long)t * NQKV + h * DH;
    if (h < HQ + HKV) {
        float x1 = row[j], x2 = row[j + 64];
        float inv = exp2f(-0.311430758889f * (float)j);   // theta^(-j/64)
        float ang = (float)pos[t] * inv;
        float c = cosf(ang), s = sinf(ang);
        float o1 = x1 * c - x2 * s;
        float o2 = x2 * c + x1 * s;
        if (h < HQ) {
            const float scale = 0.08838834764831845f * 1.4426950408889634f;  // 1/sqrt(128)*log2e
            u16* o = Qb + (long)t * D_MODEL + h * DH;
            o[j] = f2b(o1 * scale); o[j + 64] = f2b(o2 * scale);
        } else {
            u16* o = Kb + (long)t * KVD + (h - HQ) * DH;
            o[j] = f2b(o1); o[j + 64] = f2b(o2);
        }
    } else {
        int hv = h - HQ - HKV;
        VbT[(long)(hv * DH + j) * T_SEQ + t] = f2b(row[j]);
        VbT[(long)(hv * DH + j + 64) * T_SEQ + t] = f2b(row[j + 64]);
    }
}

// ---------------- flash attention, split-KV, S^T form. Block = 64 q x 512 kv chunk. ----------------
// Single-buffer Kt/Vt (cross-staged, 2 barriers/iter), swizzled Ps: 40KB LDS -> 4 blocks/CU.
__global__ __launch_bounds__(256, 4) void attn_kernel(
    const u16* __restrict__ Qb, const u16* __restrict__ Kb, const u16* __restrict__ VbT,
    u16* __restrict__ Op01, u16* __restrict__ Op23, float* __restrict__ ml)
{
    __shared__ __align__(16) u16 Kt[64 * 128];   // [kv][d], XOR-swizzled 16B blocks
    __shared__ __align__(16) u16 Vt[128 * 64];   // [d][t], XOR-swizzled
    __shared__ __align__(16) u16 Ps[4][16 * 64]; // per-wave P^T->P, XOR-swizzled, no pad
    // decode (qb, chunk): tier g has qtiles 8g..8g+7, g+1 chunks
    int bx = blockIdx.x, qb, ch;
    if (bx < 8)       { qb = bx;               ch = 0; }
    else if (bx < 24) { int j = bx - 8;  qb = 8  + (j >> 1); ch = j & 1; }
    else if (bx < 48) { int j = bx - 24; qb = 16 + j / 3;    ch = j % 3; }
    else              { int j = bx - 48; qb = 24 + (j >> 2); ch = j & 3; }
    const int h = blockIdx.y;
    const int kvh = h / GQA;
    const int q0 = qb * 64;
    const int c_lo = ch * 512;
    const int c_hi = min(c_lo + 512, q0 + 64);
    const int n_it = (c_hi - c_lo) >> 6;
    const int tid = threadIdx.x;
    const int wave = tid >> 6, lane = tid & 63;
    const int quad = lane >> 4, l16 = lane & 15;
    const int h7 = l16 & 7;
    const int qrow = q0 + wave * 16;

    auto stageK = [&](int itx) {
        int c0 = c_lo + (itx << 6);
#pragma unroll
        for (int j = 0; j < 4; j++) {                 // 4 rows x 256B per instr
            int row = wave * 16 + j * 4 + (lane >> 4);
            int gcb = ((lane & 15) & 8) | (((lane & 15) & 7) ^ (row & 7));
            gl_lds16(Kb + (long)(c0 + row) * KVD + kvh * DH + gcb * 8,
                     &Kt[(wave * 16 + j * 4) * 128]);
        }
    };
    auto stageV = [&](int itx) {
        int c0 = c_lo + (itx << 6);
#pragma unroll
        for (int j = 0; j < 4; j++) {                 // 8 rows x 128B per instr
            int row = wave * 32 + j * 8 + (lane >> 3);
            int gcb = (lane & 7) ^ (row & 7);
            gl_lds16(VbT + (long)(kvh * DH + row) * T_SEQ + c0 + gcb * 8,
                     &Vt[(wave * 32 + j * 8) * 64]);
        }
    };

    // Q as B-operand: B[n=q=l16][k=d], b128 loads
    short8 qf[4];
    const u16* qptr = Qb + (long)(qrow + l16) * D_MODEL + h * DH;
#pragma unroll
    for (int kc = 0; kc < 4; kc++)
        qf[kc] = *(const short8*)(qptr + kc * 32 + quad * 8);

    floatx4 acc_o[8] = {};                 // O^T[d = di*16+quad*4+r][q = l16]
    float m_run = -3e38f, l_run = 0.f;     // per-lane: one q row (log2 domain)
    u16* pw = &Ps[wave][0];

    stageK(0);

    for (int itx = 0; itx < n_it; itx++) {
        int c0 = c_lo + (itx << 6);
        __syncthreads();                   // A: Kt(itx) staged; Vt free (PV done)
        stageV(itx);                       // drains at barrier B
        // ---- S^T = K Q^T: lane owns q=l16, kv = mi*16+quad*4+r ----
        floatx4 s[4] = {};
#pragma unroll
        for (int kc = 0; kc < 4; kc++) {
            short8 kf[4];
            int cs = (((kc * 4 + quad) & 8)) | (((kc * 4 + quad) & 7) ^ h7);
#pragma unroll
            for (int mi = 0; mi < 4; mi++)
                kf[mi] = *(const short8*)(Kt + (mi * 16 + l16) * 128 + cs * 8);
#pragma unroll
            for (int mi = 0; mi < 4; mi++)
                s[mi] = __builtin_amdgcn_mfma_f32_16x16x32_bf16(kf[mi], qf[kc], s[mi], 0, 0, 0);
        }
        // ---- causal mask (uniform branch; only final-chunk diagonal tiles) ----
        if (c0 + 63 > qrow) {
            int qg = qrow + l16;
#pragma unroll
            for (int mi = 0; mi < 4; mi++)
#pragma unroll
                for (int r = 0; r < 4; r++)
                    if (c0 + mi * 16 + quad * 4 + r > qg) s[mi][r] = -1e30f;
        }
        // ---- per-lane online softmax (in-lane 16 + 2 cross-quad shuffles) ----
        float tm = s[0][0];
#pragma unroll
        for (int mi = 0; mi < 4; mi++)
#pragma unroll
            for (int r = 0; r < 4; r++) tm = fmaxf(tm, s[mi][r]);
        tm = fmaxf(tm, __shfl_xor(tm, 16));
        tm = fmaxf(tm, __shfl_xor(tm, 32));
        float nm = fmaxf(m_run, tm);
        float alpha = exp2f(m_run - nm);
        m_run = nm;
        float rs = 0.f;
#pragma unroll
        for (int mi = 0; mi < 4; mi++)
#pragma unroll
            for (int r = 0; r < 4; r++) {
                float p = exp2f(s[mi][r] - nm);
                s[mi][r] = p;
                rs += p;
            }
        rs += __shfl_xor(rs, 16);
        rs += __shfl_xor(rs, 32);
        l_run = l_run * alpha + rs;
        // ---- pack P (bf16 truncate via v_perm) into swizzled Ps[q][kv] ----
#pragma unroll
        for (int mi = 0; mi < 4; mi++) {
            int cb = (mi * 2 + (quad >> 1)) ^ h7;
#pragma unroll
            for (int c = 0; c < 2; c++) {
                unsigned pk = __builtin_amdgcn_perm(
                    __float_as_uint(s[mi][2 * c + 1]), __float_as_uint(s[mi][2 * c]),
                    0x07060302u);
                *(unsigned*)(pw + l16 * 64 + cb * 8 + (quad & 1) * 4 + c * 2) = pk;
            }
        }
        __syncthreads();                   // B: Vt(itx) staged; Kt reads done
        if (itx + 1 < n_it) stageK(itx + 1);   // drains at next barrier A
#pragma unroll
        for (int di = 0; di < 8; di++)
#pragma unroll
            for (int r = 0; r < 4; r++)
                acc_o[di][r] *= alpha;
        // ---- O^T += V^T P: A=V^T from Vt, B=P from Ps ----
#pragma unroll
        for (int kc = 0; kc < 2; kc++) {
            short8 pf = *(const short8*)(pw + l16 * 64 + (((kc * 4 + quad) ^ h7) << 3));
            int csv = (kc * 4 + quad) ^ h7;
#pragma unroll
            for (int di = 0; di < 8; di++) {
                short8 vf = *(const short8*)(Vt + (di * 16 + l16) * 64 + csv * 8);
                acc_o[di] = __builtin_amdgcn_mfma_f32_16x16x32_bf16(vf, pf, acc_o[di], 0, 0, 0);
            }
        }
    }
    // ---- epilogue: O^T -> wave-private Kt scratch -> coalesced b128 partial store ----
    u16* sw = Kt + wave * 16 * 128;        // 16 q rows x 128 d
#pragma unroll
    for (int di = 0; di < 8; di++)
#pragma unroll
        for (int c = 0; c < 2; c++) {
            unsigned lo = f2b(acc_o[di][2 * c]), hi = f2b(acc_o[di][2 * c + 1]);
            *(unsigned*)(sw + l16 * 128 + di * 16 + quad * 4 + c * 2) = lo | (hi << 16);
        }
    u16* Op = (ch < 2) ? (Op01 + (long)ch * OPCH) : (Op23 + (long)(ch - 2) * OPCH);
    long gbase = ((long)h * T_SEQ + qrow) * DH;
#pragma unroll
    for (int j = 0; j < 4; j++) {
        short8 v = *(const short8*)(sw + j * 512 + lane * 8);
        *(short8*)(Op + gbase + j * 512 + lane * 8) = v;
    }
    if (lane < 16) {
        int t = qrow + lane;
        float2* p = (float2*)(ml + ((long)(ch * HQ + h) * T_SEQ + t) * 2);
        float2 v; v.x = m_run; v.y = l_run;
        *p = v;
    }
}

// ---------------- combine split-KV partials (log2 domain) ----------------
__global__ __launch_bounds__(256) void reduce_kernel(
    const u16* __restrict__ Op01, const u16* __restrict__ Op23,
    const float* __restrict__ ml, u16* __restrict__ attnb)
{
    int idx = blockIdx.x * 4 + (threadIdx.x >> 6);   // one wave per (h, t)
    int h = idx >> 11, t = idx & 2047;
    int nch = (t >> 9) + 1;
    int lane = threadIdx.x & 63;
    float mv[4], lv[4];
    float m = -3e38f;
    for (int c = 0; c < nch; c++) {
        const float2* p = (const float2*)(ml + ((long)(c * HQ + h) * T_SEQ + t) * 2);
        float2 v = *p;
        mv[c] = v.x; lv[c] = v.y;
        m = fmaxf(m, v.x);
    }
    float lsum = 0.f, o0 = 0.f, o1 = 0.f;
    for (int c = 0; c < nch; c++) {
        float w = exp2f(mv[c] - m);
        lsum += w * lv[c];
        const u16* Op = (c < 2) ? (Op01 + (long)c * OPCH) : (Op23 + (long)(c - 2) * OPCH);
        const u16* p = Op + ((long)h * T_SEQ + t) * DH + lane * 2;
        o0 += w * b2f(p[0]);
        o1 += w * b2f(p[1]);
    }
    float inv = 1.0f / lsum;
    unsigned pk = (unsigned)f2b(o0 * inv) | ((unsigned)f2b(o1 * inv) << 16);
    *(unsigned*)(attnb + (long)t * D_MODEL + h * DH + lane * 2) = pk;
}

extern "C" void kernel_launch(void* const* d_in, const int* in_sizes, int n_in,
                              void* d_out, int out_size, void* d_ws, size_t ws_size,
                              hipStream_t stream) {
    const int*   positions = (const int*)d_in[0];
    const float* hidden    = (const float*)d_in[1];
    const float* Wqkv      = (const float*)d_in[2];
    const float* bqkv      = (const float*)d_in[3];
    const float* Wo        = (const float*)d_in[4];
    float* out = (float*)d_out;

    char* w = (char*)d_ws;
    u16*   woT    = (u16*)(w);                      // persist
    u16*   hid_b  = (u16*)(w + 26214400);           // dead after gemm1
    u16*   wqkvT  = (u16*)(w + 41943040);           // dead after gemm1
    float* qkv32  = (float*)(w + 75497472);         // dead after rope
    u16*   Qb     = (u16*)(w + 115343360);          // persist
    u16*   Kb     = (u16*)(w + 130023424);          // persist
    u16*   VbT    = (u16*)(w + 132120576);          // persist
    u16*   attnb  = (u16*)(w + 26214400);           // reuse hid_b region
    u16*   Op01   = (u16*)(w + 41943040);           // partial O chunks 0,1
    u16*   Op23   = (u16*)(w + 75497472);           // partial O chunks 2,3
    float* mlbuf  = (float*)(w + 105906176);        // (m,l) per (chunk,head,row)

    int nh = T_SEQ * D_MODEL;
    cvt_kernel<<<nh / 1024, 256, 0, stream>>>(hidden, hid_b, nh);
    transpose_cvt<<<dim3(NQKV / 32, D_MODEL / 32), dim3(32, 8), 0, stream>>>(Wqkv, wqkvT, D_MODEL, NQKV);
    transpose_cvt<<<dim3(D_MODEL / 32, D_MODEL / 32), dim3(32, 8), 0, stream>>>(Wo, woT, D_MODEL, D_MODEL);
    gemm_bt<<<dim3(NQKV / 128, T_SEQ / 128), 256, 0, stream>>>(hid_b, wqkvT, qkv32, bqkv,
                                                              T_SEQ, NQKV, D_MODEL);
    rope_split<<<dim3(T_SEQ, HQ + 2 * HKV), 64, 0, stream>>>(qkv32, positions, Qb, Kb, VbT);
    attn_kernel<<<dim3(80, HQ), 256, 0, stream>>>(Qb, Kb, VbT, Op01, Op23, mlbuf);
    reduce_kernel<<<T_SEQ * HQ / 4, 256, 0, stream>>>(Op01, Op23, mlbuf, attnb);
    gemm_bt<<<dim3(D_MODEL / 128, T_SEQ / 128), 256, 0, stream>>>(attnb, woT, out, nullptr,
                                                                 T_SEQ, D_MODEL, D_MODEL);
}